// Round 4
// baseline (126.860 us; speedup 1.0000x reference)
//
#include <hip/hip_runtime.h>
#include <hip/hip_fp16.h>
#include <math.h>

#define BDIM 4
#define LDIM 512
#define EDIM 1024
#define HDIM 128
#define TILE 32            // 32x32 y-tile, 33x33 s-grid (1 halo), grid 16x16x4
#define NT   16
#define K2   2.885390081777927f   // 2/ln(2)

typedef unsigned short ushort_t;
typedef __attribute__((ext_vector_type(8))) _Float16 half8;
typedef __attribute__((ext_vector_type(4))) float f32x4;

struct __align__(16) H8 { __half2 p[4]; };
union HU { H8 h; half8 v; };
struct __align__(8) US4 { ushort_t u[4]; };

// ---------------------------------------------------------------------------
// Kernel 0: prep. (a) W1 (1024x128 f32) -> w1t (128x1024 f16): B-fragment for
// the GEMM becomes ONE coalesced half8 load (col-major k-contiguous) instead
// of 8 stride-512B scalar loads. Reads coalesced (lanes = cols). (b) block 0
// also builds wneg[16][128] (-2*w_tap f16, rows>=4 zero) + wsumg[4].
// ---------------------------------------------------------------------------
__global__ __launch_bounds__(256) void prep(
    const float* __restrict__ W1, const float* __restrict__ cw,
    ushort_t* __restrict__ w1t, ushort_t* __restrict__ wneg,
    float* __restrict__ wsumg) {
  const int t = threadIdx.x;
  const int tid = (int)blockIdx.x * 256 + t;   // 64 blocks * 256 = 16384
  const int col = tid & 127;                   // lane-contiguous -> coalesced reads
  const int k8 = (tid >> 7) * 8;
  HU hu;
#pragma unroll
  for (int e = 0; e < 4; ++e) {
    float a = W1[(size_t)(k8 + 2 * e) * HDIM + col];
    float b = W1[(size_t)(k8 + 2 * e + 1) * HDIM + col];
    hu.h.p[e] = __floats2half2_rn(a, b);
  }
  *(half8*)&w1t[(size_t)col * EDIM + k8] = hu.v;

  if (blockIdx.x == 0) {
    __shared__ float wp[2][4];
    if (t < HDIM) {
      float4 w4 = *(const float4*)&cw[t * 4];
      _Float16 h0 = (_Float16)(-2.f * w4.x), h1 = (_Float16)(-2.f * w4.y);
      _Float16 h2 = (_Float16)(-2.f * w4.z), h3 = (_Float16)(-2.f * w4.w);
      wneg[0 * HDIM + t] = *(ushort_t*)&h0;
      wneg[1 * HDIM + t] = *(ushort_t*)&h1;
      wneg[2 * HDIM + t] = *(ushort_t*)&h2;
      wneg[3 * HDIM + t] = *(ushort_t*)&h3;
#pragma unroll
      for (int k = 4; k < 16; ++k) wneg[k * HDIM + t] = 0;
      float4 ws = w4;
#pragma unroll
      for (int off = 32; off > 0; off >>= 1) {
        ws.x += __shfl_down(ws.x, off, 64);
        ws.y += __shfl_down(ws.y, off, 64);
        ws.z += __shfl_down(ws.z, off, 64);
        ws.w += __shfl_down(ws.w, off, 64);
      }
      if ((t & 63) == 0) {
        wp[t >> 6][0] = ws.x; wp[t >> 6][1] = ws.y;
        wp[t >> 6][2] = ws.z; wp[t >> 6][3] = ws.w;
      }
    }
    __syncthreads();
    if (t < 4) wsumg[t] = wp[0][t] + wp[1][t];
  }
}

// ---------------------------------------------------------------------------
// Kernel 1: hid = relu(emb @ W1 + b1) f16 (rec rows * -K2). B from w1t f16:
// 4 half8 loads per K-block (96 VMEM instr/wave, was 324). unroll 2 overlaps
// next-blk loads with cvt+MFMA (2 waves/SIMD -> need ILP).
// ---------------------------------------------------------------------------
__global__ __launch_bounds__(256) void gemm_direct(
    const float* __restrict__ rec, const float* __restrict__ lig,
    const ushort_t* __restrict__ w1t, const float* __restrict__ b1,
    ushort_t* __restrict__ hid) {
  const int gw = (int)blockIdx.x * 4 + (threadIdx.x >> 6);
  const int l = threadIdx.x & 63;
  const int strip = gw >> 3;
  const int nidx = gw & 7;
  const int r0 = strip * 16;
  const int m = l & 15, q = l >> 4;
  const float* arow = ((r0 < BDIM * LDIM)
                           ? rec + (size_t)r0 * EDIM
                           : lig + (size_t)(r0 - BDIM * LDIM) * EDIM) +
                      (size_t)m * EDIM + q * 8;
  const int col = nidx * 16 + m;
  const ushort_t* wrow = w1t + (size_t)col * EDIM + q * 8;

  f32x4 acc = {0.f, 0.f, 0.f, 0.f};
#pragma unroll 2
  for (int blk = 0; blk < 8; ++blk) {
    float4 alo[4], ahi[4];
    half8 bv[4];
#pragma unroll
    for (int j = 0; j < 4; ++j) {
      alo[j] = *(const float4*)(arow + (blk * 4 + j) * 32);
      ahi[j] = *(const float4*)(arow + (blk * 4 + j) * 32 + 4);
      bv[j] = *(const half8*)&wrow[(blk * 4 + j) * 32];
    }
#pragma unroll
    for (int j = 0; j < 4; ++j) {
      HU au;
      au.h.p[0] = __floats2half2_rn(alo[j].x, alo[j].y);
      au.h.p[1] = __floats2half2_rn(alo[j].z, alo[j].w);
      au.h.p[2] = __floats2half2_rn(ahi[j].x, ahi[j].y);
      au.h.p[3] = __floats2half2_rn(ahi[j].z, ahi[j].w);
      acc = __builtin_amdgcn_mfma_f32_16x16x32_f16(au.v, bv[j], acc, 0, 0, 0);
    }
  }
  const float scale = (r0 < BDIM * LDIM) ? -K2 : 1.0f;
  const float bias = b1[col];
#pragma unroll
  for (int r = 0; r < 4; ++r) {
    float v = fmaxf(acc[r] + bias, 0.f) * scale;
    ((_Float16*)hid)[(size_t)(r0 + q * 4 + r) * HDIM + col] = (_Float16)v;
  }
}

// ---------------------------------------------------------------------------
// Kernel 2 (round-3 exact): 32x32 y-tile, 512-thread/8-wave blocks, grid 1024
// -> 4 blocks/CU x 8 waves = 32 waves/CU. launch_bounds(512,8) pins VGPR<=64.
// Wave w covers ii in [4w,4w+4). Edge strips parallelized 4x, barrier-free.
// ---------------------------------------------------------------------------
__global__ __launch_bounds__(512, 8) void bilinear_max(
    const ushort_t* __restrict__ hid, const ushort_t* __restrict__ wneg,
    const float* __restrict__ wsumg, const float* __restrict__ cw,
    const float* __restrict__ cb, float* __restrict__ partial) {
  __shared__ ushort_t rl[33][130];     // 65-dword row stride
  __shared__ ushort_t ll[33][130];
  __shared__ ushort_t sl4[33][34][4];  // f16 taps {s00,s01,s10,s11}
  __shared__ float wred[8];

  const int t = threadIdx.x;
  const int b = blockIdx.z;
  const int ib = (int)blockIdx.y * TILE - 1;
  const int jb = (int)blockIdx.x * TILE - 1;
  const int w = t >> 6, l = t & 63;
  const int q = l >> 4, c15 = l & 15;

  half8 wf[4];
#pragma unroll
  for (int c = 0; c < 4; ++c)
    wf[c] = *(const half8*)&wneg[c15 * HDIM + c * 32 + q * 8];
  const float wsum_v = (c15 < 4) ? wsumg[c15] : 0.f;

  // stage 33+33 rows x 16 octets
  H8 z;
  z.p[0] = z.p[1] = z.p[2] = z.p[3] = __floats2half2_rn(0.f, 0.f);
  for (int p = t; p < 66 * 16; p += 512) {
    int r = p >> 4, seg = (p & 15) * 8;
    if (r < 33) {
      int i = ib + r;
      H8 v = z;
      if (i >= 0) v = *(const H8*)&hid[((size_t)(b * LDIM + i)) * HDIM + seg];
      *(H8*)&rl[r][seg] = v;
    } else {
      int j = jb + (r - 33);
      H8 v = z;
      if (j >= 0) v = *(const H8*)&hid[((size_t)((BDIM + b) * LDIM + j)) * HDIM + seg];
      *(H8*)&ll[r - 33][seg] = v;
    }
  }
  __syncthreads();

  const __half2 E0 = __float2half2_rn(0.991381f);
  const __half2 E1 = __float2half2_rn(-0.818328f);
  const __half2 E2 = __float2half2_rn(0.333048f);
#define POLYG(U) __hmul2(U, __hfma2(U, __hfma2(U, E2, E1), E0))
#define GCHAIN(GU, RU, LU)                                                    \
  {                                                                           \
    __half2 u0 = h2exp2(__hmul2((RU).h.p[0], (LU).h.p[0]));                   \
    __half2 u1 = h2exp2(__hmul2((RU).h.p[1], (LU).h.p[1]));                   \
    __half2 u2 = h2exp2(__hmul2((RU).h.p[2], (LU).h.p[2]));                   \
    __half2 u3 = h2exp2(__hmul2((RU).h.p[3], (LU).h.p[3]));                   \
    (GU).h.p[0] = POLYG(u0);                                                  \
    (GU).h.p[1] = POLYG(u1);                                                  \
    (GU).h.p[2] = POLYG(u2);                                                  \
    (GU).h.p[3] = POLYG(u3);                                                  \
  }

  // phase B: wave w covers ii in [4w, 4w+4); 4 independent chains.
#pragma unroll
  for (int hf = 0; hf < 2; ++hf) {
    const int jj0 = hf << 4;
    HU lu[4];
#pragma unroll
    for (int c = 0; c < 4; ++c)
      lu[c].v = *(const half8*)&ll[jj0 + c15][c * 32 + q * 8];
    const int ii = w * 4;
    f32x4 a0 = {0.f, 0.f, 0.f, 0.f}, a1 = a0, a2 = a0, a3 = a0;
#pragma unroll
    for (int c = 0; c < 4; ++c) {
      HU r0, r1, r2, r3, g0, g1, g2, g3;
      r0.v = *(const half8*)&rl[ii + 0][c * 32 + q * 8];
      r1.v = *(const half8*)&rl[ii + 1][c * 32 + q * 8];
      r2.v = *(const half8*)&rl[ii + 2][c * 32 + q * 8];
      r3.v = *(const half8*)&rl[ii + 3][c * 32 + q * 8];
      GCHAIN(g0, r0, lu[c])
      GCHAIN(g1, r1, lu[c])
      GCHAIN(g2, r2, lu[c])
      GCHAIN(g3, r3, lu[c])
      a0 = __builtin_amdgcn_mfma_f32_16x16x32_f16(g0.v, wf[c], a0, 0, 0, 0);
      a1 = __builtin_amdgcn_mfma_f32_16x16x32_f16(g1.v, wf[c], a1, 0, 0, 0);
      a2 = __builtin_amdgcn_mfma_f32_16x16x32_f16(g2.v, wf[c], a2, 0, 0, 0);
      a3 = __builtin_amdgcn_mfma_f32_16x16x32_f16(g3.v, wf[c], a3, 0, 0, 0);
    }
    if (c15 < 4) {
#pragma unroll
      for (int r = 0; r < 4; ++r) {
        _Float16 h0 = (_Float16)(wsum_v + a0[r]);
        _Float16 h1 = (_Float16)(wsum_v + a1[r]);
        _Float16 h2 = (_Float16)(wsum_v + a2[r]);
        _Float16 h3 = (_Float16)(wsum_v + a3[r]);
        sl4[ii + 0][jj0 + q * 4 + r][c15] = *(ushort_t*)&h0;
        sl4[ii + 1][jj0 + q * 4 + r][c15] = *(ushort_t*)&h1;
        sl4[ii + 2][jj0 + q * 4 + r][c15] = *(ushort_t*)&h2;
        sl4[ii + 3][jj0 + q * 4 + r][c15] = *(ushort_t*)&h3;
      }
    }
  }
#undef GCHAIN
#undef POLYG

  // edge strips (no barrier needed: disjoint sl4 region from phase B).
  // 65 pairs x 4 lanes (32 h each) over threads 0..259, shfl_xor reduce.
  if (t < 260) {
    const int pr = t >> 2;
    const int o = t & 3;
    const int pi = (pr < 33) ? pr : 32;
    const int qj = (pr < 33) ? 32 : (pr - 33);
    float sa0 = 0.f, sa1 = 0.f, sa2 = 0.f, sa3 = 0.f;
    const int hb = o * 32;
    for (int h8 = hb; h8 < hb + 32; h8 += 8) {
      HU r8, l8;
      r8.v = *(const half8*)&rl[pi][h8];
      l8.v = *(const half8*)&ll[qj][h8];
#pragma unroll
      for (int j = 0; j < 4; ++j) {
        float2 pf = __half22float2(__hmul2(r8.h.p[j], l8.h.p[j]));
        float u0 = __builtin_amdgcn_exp2f(pf.x);
        float u1 = __builtin_amdgcn_exp2f(pf.y);
        float g0 = u0 * fmaf(u0, fmaf(u0, 0.333048f, -0.818328f), 0.991381f);
        float g1 = u1 * fmaf(u1, fmaf(u1, 0.333048f, -0.818328f), 0.991381f);
        float4 wa = *(const float4*)&cw[(h8 + 2 * j) * 4];
        float4 wb = *(const float4*)&cw[(h8 + 2 * j + 1) * 4];
        sa0 = fmaf(-2.f * g0, wa.x, fmaf(-2.f * g1, wb.x, sa0));
        sa1 = fmaf(-2.f * g0, wa.y, fmaf(-2.f * g1, wb.y, sa1));
        sa2 = fmaf(-2.f * g0, wa.z, fmaf(-2.f * g1, wb.z, sa2));
        sa3 = fmaf(-2.f * g0, wa.w, fmaf(-2.f * g1, wb.w, sa3));
      }
    }
    sa0 += __shfl_xor(sa0, 1, 64);
    sa1 += __shfl_xor(sa1, 1, 64);
    sa2 += __shfl_xor(sa2, 1, 64);
    sa3 += __shfl_xor(sa3, 1, 64);
    sa0 += __shfl_xor(sa0, 2, 64);
    sa1 += __shfl_xor(sa1, 2, 64);
    sa2 += __shfl_xor(sa2, 2, 64);
    sa3 += __shfl_xor(sa3, 2, 64);
    if (o == 0) {
      _Float16 h0 = (_Float16)(wsumg[0] + sa0);
      _Float16 h1 = (_Float16)(wsumg[1] + sa1);
      _Float16 h2 = (_Float16)(wsumg[2] + sa2);
      _Float16 h3 = (_Float16)(wsumg[3] + sa3);
      US4 s;
      s.u[0] = *(ushort_t*)&h0; s.u[1] = *(ushort_t*)&h1;
      s.u[2] = *(ushort_t*)&h2; s.u[3] = *(ushort_t*)&h3;
      *(US4*)&sl4[pi][qj][0] = s;
    }
  }
  __syncthreads();

  // phase C: y = cb + s00(iy-1,jj-1)+s01(iy-1,jj)+s10(iy,jj-1)+s11(iy,jj)
  float m = -INFINITY;
  const float cbv = cb[0];
  for (int p = t; p < TILE * TILE; p += 512) {
    int jj = (p & 31) + 1, iy = (p >> 5) + 1;
    float v = cbv + (float)(*(const _Float16*)&sl4[iy - 1][jj - 1][0])
                  + (float)(*(const _Float16*)&sl4[iy - 1][jj][1])
                  + (float)(*(const _Float16*)&sl4[iy][jj - 1][2])
                  + (float)(*(const _Float16*)&sl4[iy][jj][3]);
    m = fmaxf(m, v);
  }
#pragma unroll
  for (int off = 32; off > 0; off >>= 1) m = fmaxf(m, __shfl_down(m, off, 64));
  if ((t & 63) == 0) wred[t >> 6] = m;
  __syncthreads();
  if (t == 0) {
    float mm = wred[0];
#pragma unroll
    for (int i = 1; i < 8; ++i) mm = fmaxf(mm, wred[i]);
    partial[((size_t)b * NT + blockIdx.y) * NT + blockIdx.x] = mm;
  }
}

// ---------------------------------------------------------------------------
// Kernel 3: reduce 16x16 partials per batch, sigmoid, write 4 outputs.
// ---------------------------------------------------------------------------
__global__ __launch_bounds__(64) void finalize(const float* __restrict__ partial,
                                               float* __restrict__ out) {
  const int b = blockIdx.x, t = threadIdx.x;
  float m = -INFINITY;
  for (int p = t; p < NT * NT; p += 64) m = fmaxf(m, partial[b * NT * NT + p]);
#pragma unroll
  for (int off = 32; off > 0; off >>= 1) m = fmaxf(m, __shfl_down(m, off, 64));
  if (t == 0) out[b] = 1.f / (1.f + expf(-m));
}

extern "C" void kernel_launch(void* const* d_in, const int* in_sizes, int n_in,
                              void* d_out, int out_size, void* d_ws, size_t ws_size,
                              hipStream_t stream) {
  const float* rec = (const float*)d_in[0];
  const float* lig = (const float*)d_in[1];
  const float* W1  = (const float*)d_in[2];
  const float* b1  = (const float*)d_in[3];
  const float* cw  = (const float*)d_in[4];   // (1,H,2,2): {w00,w01,w10,w11} per h
  const float* cb  = (const float*)d_in[5];
  float* out = (float*)d_out;

  ushort_t* hid  = (ushort_t*)d_ws;                        // 4096x128 f16 = 1 MB
  float* partial = (float*)(hid + (size_t)2 * BDIM * LDIM * HDIM);  // 1024 f32
  ushort_t* wneg = (ushort_t*)(partial + NT * NT * BDIM);  // 16x128 f16 = 4 KB
  float* wsumg   = (float*)(wneg + 16 * HDIM);             // 4 f32
  ushort_t* w1t  = (ushort_t*)(wsumg + 4);                 // 128x1024 f16 = 256 KB

  prep<<<dim3(64), 256, 0, stream>>>(W1, cw, w1t, wneg, wsumg);
  gemm_direct<<<dim3(512), 256, 0, stream>>>(rec, lig, w1t, b1, hid);
  bilinear_max<<<dim3(NT, NT, BDIM), 512, 0, stream>>>(hid, wneg, wsumg, cw, cb, partial);
  finalize<<<dim3(BDIM), 64, 0, stream>>>(partial, out);
}

// Round 5
// 112.601 us; speedup vs baseline: 1.1266x; 1.1266x over previous
//
#include <hip/hip_runtime.h>
#include <hip/hip_fp16.h>
#include <math.h>

#define BDIM 4
#define LDIM 512
#define EDIM 1024
#define HDIM 128
#define TILE 32            // 32x32 y-tile, 33x33 s-grid (1 halo), grid 16x16x4
#define NT   16
#define K2   2.885390081777927f   // 2/ln(2)

typedef unsigned short ushort_t;
typedef __attribute__((ext_vector_type(8))) _Float16 half8;
typedef __attribute__((ext_vector_type(4))) float f32x4;

struct __align__(16) H8 { __half2 p[4]; };
union HU { H8 h; half8 v; };
struct __align__(8) US4 { ushort_t u[4]; };

// ---------------------------------------------------------------------------
// Kernel 1: LDS-staged GEMM. hid = relu(emb @ W1 + b1) f16 (rec rows * -K2).
// 256 blocks x 256 thr: block = 16-row strip x 128 cols, K=1024.
//  - A strip -> Al[16][1026] f16 (odd dw stride 513: ~2-way banks), coalesced
//    float4 loads (16 instr/wave).
//  - W1 K-chunks (128) -> Bl[2][128][130] f16 TRANSPOSED [col][k] (stride 65
//    dw, odd), coalesced row loads prefetched to regs, k-pair __half2 writes.
//  - Fragments via ds_read_b128 (4B-aligned LDS b128 proven by bilinear).
// VMEM/wave: 144 coalesced (was 320 scattered: TA-bound ~25us).
// hid bit-identical to round-0 path (same values, same K order).
// Block 0 also preps wneg[16][128] + wsumg[4].
// ---------------------------------------------------------------------------
__global__ __launch_bounds__(256) void gemm_lds(
    const float* __restrict__ rec, const float* __restrict__ lig,
    const float* __restrict__ W1, const float* __restrict__ b1,
    const float* __restrict__ cw, ushort_t* __restrict__ hid,
    ushort_t* __restrict__ wneg, float* __restrict__ wsumg) {
  __shared__ ushort_t Al[16][1026];        // 32.8 KB, row stride 513 dw (odd)
  __shared__ ushort_t Bl[2][128][130];     // 66.6 KB, row stride 65 dw (odd)
  __shared__ float wp[2][4];

  const int t = threadIdx.x;

  if (blockIdx.x == 0) {                   // fold wneg/wsumg prep into block 0
    if (t < HDIM) {
      float4 w4 = *(const float4*)&cw[t * 4];
      _Float16 h0 = (_Float16)(-2.f * w4.x), h1 = (_Float16)(-2.f * w4.y);
      _Float16 h2 = (_Float16)(-2.f * w4.z), h3 = (_Float16)(-2.f * w4.w);
      wneg[0 * HDIM + t] = *(ushort_t*)&h0;
      wneg[1 * HDIM + t] = *(ushort_t*)&h1;
      wneg[2 * HDIM + t] = *(ushort_t*)&h2;
      wneg[3 * HDIM + t] = *(ushort_t*)&h3;
#pragma unroll
      for (int k = 4; k < 16; ++k) wneg[k * HDIM + t] = 0;
      float4 ws = w4;
#pragma unroll
      for (int off = 32; off > 0; off >>= 1) {
        ws.x += __shfl_down(ws.x, off, 64);
        ws.y += __shfl_down(ws.y, off, 64);
        ws.z += __shfl_down(ws.z, off, 64);
        ws.w += __shfl_down(ws.w, off, 64);
      }
      if ((t & 63) == 0) {
        wp[t >> 6][0] = ws.x; wp[t >> 6][1] = ws.y;
        wp[t >> 6][2] = ws.z; wp[t >> 6][3] = ws.w;
      }
    }
    __syncthreads();
    if (t < 4) wsumg[t] = wp[0][t] + wp[1][t];
  }

  const int r0 = (int)blockIdx.x * 16;     // strip rows r0..r0+15
  const float* abase = (r0 < BDIM * LDIM)
                           ? rec + (size_t)r0 * EDIM
                           : lig + (size_t)(r0 - BDIM * LDIM) * EDIM;

  // ---- stage A strip: 16 rows x 1024 f32 -> f16. thread t: row t>>4,
  // cols (t&15)*4 + p*64 (lanes contiguous 256B per row). Banks ~2-way.
  {
    const int sr = t >> 4, su = t & 15;
    const float* ar = abase + (size_t)sr * EDIM;
#pragma unroll
    for (int p = 0; p < 16; ++p) {
      const int c = su * 4 + p * 64;
      f32x4 v = *(const f32x4*)(ar + c);
      *(__half2*)&Al[sr][c] = __floats2half2_rn(v[0], v[1]);
      *(__half2*)&Al[sr][c + 2] = __floats2half2_rn(v[2], v[3]);
    }
  }

  // ---- stage B chunk 0: rows 0..127 of W1 -> Bl[0] transposed [col][k].
  // pass p: thread t: k-pair kp = p*8 + (t>>5), cols (t&31)*4..+3.
  const int cu4 = (t & 31) * 4, kg = t >> 5;
  {
#pragma unroll
    for (int p = 0; p < 8; ++p) {
      const int kp = p * 8 + kg;
      f32x4 ra = *(const f32x4*)(W1 + (size_t)(2 * kp) * HDIM + cu4);
      f32x4 rb = *(const f32x4*)(W1 + (size_t)(2 * kp + 1) * HDIM + cu4);
#pragma unroll
      for (int i = 0; i < 4; ++i)
        *(__half2*)&Bl[0][cu4 + i][2 * kp] = __floats2half2_rn(ra[i], rb[i]);
    }
  }
  __syncthreads();

  const int w = t >> 6, l = t & 63;
  const int m = l & 15, q = l >> 4;
  const int tc0 = 32 * w;                  // wave's col base (2 tiles of 16)

  f32x4 acc0 = {0.f, 0.f, 0.f, 0.f}, acc1 = acc0;
  for (int kc = 0; kc < 8; ++kc) {
    const int bb = kc & 1;
    f32x4 sa[8], sb[8];
    if (kc < 7) {                          // prefetch next chunk to regs
      const float* wb = W1 + (size_t)((kc + 1) * 128) * HDIM;
#pragma unroll
      for (int p = 0; p < 8; ++p) {
        const int kp = p * 8 + kg;
        sa[p] = *(const f32x4*)(wb + (size_t)(2 * kp) * HDIM + cu4);
        sb[p] = *(const f32x4*)(wb + (size_t)(2 * kp + 1) * HDIM + cu4);
      }
    }
    // compute chunk kc: 4 k-steps x 2 col-tiles (A-frag shared)
#pragma unroll
    for (int s = 0; s < 4; ++s) {
      const int kof = s * 32 + q * 8;
      half8 af = *(const half8*)&Al[m][kc * 128 + kof];
      half8 b0 = *(const half8*)&Bl[bb][tc0 + m][kof];
      half8 b1v = *(const half8*)&Bl[bb][tc0 + 16 + m][kof];
      acc0 = __builtin_amdgcn_mfma_f32_16x16x32_f16(af, b0, acc0, 0, 0, 0);
      acc1 = __builtin_amdgcn_mfma_f32_16x16x32_f16(af, b1v, acc1, 0, 0, 0);
    }
    if (kc < 7) {                          // drain prefetch into other buffer
#pragma unroll
      for (int p = 0; p < 8; ++p) {
        const int kp = p * 8 + kg;
#pragma unroll
        for (int i = 0; i < 4; ++i)
          *(__half2*)&Bl[bb ^ 1][cu4 + i][2 * kp] =
              __floats2half2_rn(sa[p][i], sb[p][i]);
      }
    }
    __syncthreads();
  }

  const float scale = (r0 < BDIM * LDIM) ? -K2 : 1.0f;
  const float bias0 = b1[tc0 + m];
  const float bias1 = b1[tc0 + 16 + m];
#pragma unroll
  for (int r = 0; r < 4; ++r) {
    const int row = r0 + q * 4 + r;
    float v0 = fmaxf(acc0[r] + bias0, 0.f) * scale;
    float v1 = fmaxf(acc1[r] + bias1, 0.f) * scale;
    ((_Float16*)hid)[(size_t)row * HDIM + tc0 + m] = (_Float16)v0;
    ((_Float16*)hid)[(size_t)row * HDIM + tc0 + 16 + m] = (_Float16)v1;
  }
}

// ---------------------------------------------------------------------------
// Kernel 2 (round-3 exact): 32x32 y-tile, 512-thread/8-wave blocks, grid 1024
// -> 4 blocks/CU x 8 waves = 32 waves/CU. launch_bounds(512,8) pins VGPR<=64.
// Wave w covers ii in [4w,4w+4). Edge strips parallelized 4x, barrier-free.
// ---------------------------------------------------------------------------
__global__ __launch_bounds__(512, 8) void bilinear_max(
    const ushort_t* __restrict__ hid, const ushort_t* __restrict__ wneg,
    const float* __restrict__ wsumg, const float* __restrict__ cw,
    const float* __restrict__ cb, float* __restrict__ partial) {
  __shared__ ushort_t rl[33][130];     // 65-dword row stride
  __shared__ ushort_t ll[33][130];
  __shared__ ushort_t sl4[33][34][4];  // f16 taps {s00,s01,s10,s11}
  __shared__ float wred[8];

  const int t = threadIdx.x;
  const int b = blockIdx.z;
  const int ib = (int)blockIdx.y * TILE - 1;
  const int jb = (int)blockIdx.x * TILE - 1;
  const int w = t >> 6, l = t & 63;
  const int q = l >> 4, c15 = l & 15;

  half8 wf[4];
#pragma unroll
  for (int c = 0; c < 4; ++c)
    wf[c] = *(const half8*)&wneg[c15 * HDIM + c * 32 + q * 8];
  const float wsum_v = (c15 < 4) ? wsumg[c15] : 0.f;

  // stage 33+33 rows x 16 octets
  H8 z;
  z.p[0] = z.p[1] = z.p[2] = z.p[3] = __floats2half2_rn(0.f, 0.f);
  for (int p = t; p < 66 * 16; p += 512) {
    int r = p >> 4, seg = (p & 15) * 8;
    if (r < 33) {
      int i = ib + r;
      H8 v = z;
      if (i >= 0) v = *(const H8*)&hid[((size_t)(b * LDIM + i)) * HDIM + seg];
      *(H8*)&rl[r][seg] = v;
    } else {
      int j = jb + (r - 33);
      H8 v = z;
      if (j >= 0) v = *(const H8*)&hid[((size_t)((BDIM + b) * LDIM + j)) * HDIM + seg];
      *(H8*)&ll[r - 33][seg] = v;
    }
  }
  __syncthreads();

  const __half2 E0 = __float2half2_rn(0.991381f);
  const __half2 E1 = __float2half2_rn(-0.818328f);
  const __half2 E2 = __float2half2_rn(0.333048f);
#define POLYG(U) __hmul2(U, __hfma2(U, __hfma2(U, E2, E1), E0))
#define GCHAIN(GU, RU, LU)                                                    \
  {                                                                           \
    __half2 u0 = h2exp2(__hmul2((RU).h.p[0], (LU).h.p[0]));                   \
    __half2 u1 = h2exp2(__hmul2((RU).h.p[1], (LU).h.p[1]));                   \
    __half2 u2 = h2exp2(__hmul2((RU).h.p[2], (LU).h.p[2]));                   \
    __half2 u3 = h2exp2(__hmul2((RU).h.p[3], (LU).h.p[3]));                   \
    (GU).h.p[0] = POLYG(u0);                                                  \
    (GU).h.p[1] = POLYG(u1);                                                  \
    (GU).h.p[2] = POLYG(u2);                                                  \
    (GU).h.p[3] = POLYG(u3);                                                  \
  }

  // phase B: wave w covers ii in [4w, 4w+4); 4 independent chains.
#pragma unroll
  for (int hf = 0; hf < 2; ++hf) {
    const int jj0 = hf << 4;
    HU lu[4];
#pragma unroll
    for (int c = 0; c < 4; ++c)
      lu[c].v = *(const half8*)&ll[jj0 + c15][c * 32 + q * 8];
    const int ii = w * 4;
    f32x4 a0 = {0.f, 0.f, 0.f, 0.f}, a1 = a0, a2 = a0, a3 = a0;
#pragma unroll
    for (int c = 0; c < 4; ++c) {
      HU r0, r1, r2, r3, g0, g1, g2, g3;
      r0.v = *(const half8*)&rl[ii + 0][c * 32 + q * 8];
      r1.v = *(const half8*)&rl[ii + 1][c * 32 + q * 8];
      r2.v = *(const half8*)&rl[ii + 2][c * 32 + q * 8];
      r3.v = *(const half8*)&rl[ii + 3][c * 32 + q * 8];
      GCHAIN(g0, r0, lu[c])
      GCHAIN(g1, r1, lu[c])
      GCHAIN(g2, r2, lu[c])
      GCHAIN(g3, r3, lu[c])
      a0 = __builtin_amdgcn_mfma_f32_16x16x32_f16(g0.v, wf[c], a0, 0, 0, 0);
      a1 = __builtin_amdgcn_mfma_f32_16x16x32_f16(g1.v, wf[c], a1, 0, 0, 0);
      a2 = __builtin_amdgcn_mfma_f32_16x16x32_f16(g2.v, wf[c], a2, 0, 0, 0);
      a3 = __builtin_amdgcn_mfma_f32_16x16x32_f16(g3.v, wf[c], a3, 0, 0, 0);
    }
    if (c15 < 4) {
#pragma unroll
      for (int r = 0; r < 4; ++r) {
        _Float16 h0 = (_Float16)(wsum_v + a0[r]);
        _Float16 h1 = (_Float16)(wsum_v + a1[r]);
        _Float16 h2 = (_Float16)(wsum_v + a2[r]);
        _Float16 h3 = (_Float16)(wsum_v + a3[r]);
        sl4[ii + 0][jj0 + q * 4 + r][c15] = *(ushort_t*)&h0;
        sl4[ii + 1][jj0 + q * 4 + r][c15] = *(ushort_t*)&h1;
        sl4[ii + 2][jj0 + q * 4 + r][c15] = *(ushort_t*)&h2;
        sl4[ii + 3][jj0 + q * 4 + r][c15] = *(ushort_t*)&h3;
      }
    }
  }
#undef GCHAIN
#undef POLYG

  // edge strips (no barrier needed: disjoint sl4 region from phase B).
  // 65 pairs x 4 lanes (32 h each) over threads 0..259, shfl_xor reduce.
  if (t < 260) {
    const int pr = t >> 2;
    const int o = t & 3;
    const int pi = (pr < 33) ? pr : 32;
    const int qj = (pr < 33) ? 32 : (pr - 33);
    float sa0 = 0.f, sa1 = 0.f, sa2 = 0.f, sa3 = 0.f;
    const int hb = o * 32;
    for (int h8 = hb; h8 < hb + 32; h8 += 8) {
      HU r8, l8;
      r8.v = *(const half8*)&rl[pi][h8];
      l8.v = *(const half8*)&ll[qj][h8];
#pragma unroll
      for (int j = 0; j < 4; ++j) {
        float2 pf = __half22float2(__hmul2(r8.h.p[j], l8.h.p[j]));
        float u0 = __builtin_amdgcn_exp2f(pf.x);
        float u1 = __builtin_amdgcn_exp2f(pf.y);
        float g0 = u0 * fmaf(u0, fmaf(u0, 0.333048f, -0.818328f), 0.991381f);
        float g1 = u1 * fmaf(u1, fmaf(u1, 0.333048f, -0.818328f), 0.991381f);
        float4 wa = *(const float4*)&cw[(h8 + 2 * j) * 4];
        float4 wb = *(const float4*)&cw[(h8 + 2 * j + 1) * 4];
        sa0 = fmaf(-2.f * g0, wa.x, fmaf(-2.f * g1, wb.x, sa0));
        sa1 = fmaf(-2.f * g0, wa.y, fmaf(-2.f * g1, wb.y, sa1));
        sa2 = fmaf(-2.f * g0, wa.z, fmaf(-2.f * g1, wb.z, sa2));
        sa3 = fmaf(-2.f * g0, wa.w, fmaf(-2.f * g1, wb.w, sa3));
      }
    }
    sa0 += __shfl_xor(sa0, 1, 64);
    sa1 += __shfl_xor(sa1, 1, 64);
    sa2 += __shfl_xor(sa2, 1, 64);
    sa3 += __shfl_xor(sa3, 1, 64);
    sa0 += __shfl_xor(sa0, 2, 64);
    sa1 += __shfl_xor(sa1, 2, 64);
    sa2 += __shfl_xor(sa2, 2, 64);
    sa3 += __shfl_xor(sa3, 2, 64);
    if (o == 0) {
      _Float16 h0 = (_Float16)(wsumg[0] + sa0);
      _Float16 h1 = (_Float16)(wsumg[1] + sa1);
      _Float16 h2 = (_Float16)(wsumg[2] + sa2);
      _Float16 h3 = (_Float16)(wsumg[3] + sa3);
      US4 s;
      s.u[0] = *(ushort_t*)&h0; s.u[1] = *(ushort_t*)&h1;
      s.u[2] = *(ushort_t*)&h2; s.u[3] = *(ushort_t*)&h3;
      *(US4*)&sl4[pi][qj][0] = s;
    }
  }
  __syncthreads();

  // phase C: y = cb + s00(iy-1,jj-1)+s01(iy-1,jj)+s10(iy,jj-1)+s11(iy,jj)
  float m = -INFINITY;
  const float cbv = cb[0];
  for (int p = t; p < TILE * TILE; p += 512) {
    int jj = (p & 31) + 1, iy = (p >> 5) + 1;
    float v = cbv + (float)(*(const _Float16*)&sl4[iy - 1][jj - 1][0])
                  + (float)(*(const _Float16*)&sl4[iy - 1][jj][1])
                  + (float)(*(const _Float16*)&sl4[iy][jj - 1][2])
                  + (float)(*(const _Float16*)&sl4[iy][jj][3]);
    m = fmaxf(m, v);
  }
#pragma unroll
  for (int off = 32; off > 0; off >>= 1) m = fmaxf(m, __shfl_down(m, off, 64));
  if ((t & 63) == 0) wred[t >> 6] = m;
  __syncthreads();
  if (t == 0) {
    float mm = wred[0];
#pragma unroll
    for (int i = 1; i < 8; ++i) mm = fmaxf(mm, wred[i]);
    partial[((size_t)b * NT + blockIdx.y) * NT + blockIdx.x] = mm;
  }
}

// ---------------------------------------------------------------------------
// Kernel 3: reduce 16x16 partials per batch, sigmoid, write 4 outputs.
// ---------------------------------------------------------------------------
__global__ __launch_bounds__(64) void finalize(const float* __restrict__ partial,
                                               float* __restrict__ out) {
  const int b = blockIdx.x, t = threadIdx.x;
  float m = -INFINITY;
  for (int p = t; p < NT * NT; p += 64) m = fmaxf(m, partial[b * NT * NT + p]);
#pragma unroll
  for (int off = 32; off > 0; off >>= 1) m = fmaxf(m, __shfl_down(m, off, 64));
  if (t == 0) out[b] = 1.f / (1.f + expf(-m));
}

extern "C" void kernel_launch(void* const* d_in, const int* in_sizes, int n_in,
                              void* d_out, int out_size, void* d_ws, size_t ws_size,
                              hipStream_t stream) {
  const float* rec = (const float*)d_in[0];
  const float* lig = (const float*)d_in[1];
  const float* W1  = (const float*)d_in[2];
  const float* b1  = (const float*)d_in[3];
  const float* cw  = (const float*)d_in[4];   // (1,H,2,2): {w00,w01,w10,w11} per h
  const float* cb  = (const float*)d_in[5];
  float* out = (float*)d_out;

  ushort_t* hid  = (ushort_t*)d_ws;                        // 4096x128 f16 = 1 MB
  float* partial = (float*)(hid + (size_t)2 * BDIM * LDIM * HDIM);  // 1024 f32
  ushort_t* wneg = (ushort_t*)(partial + NT * NT * BDIM);  // 16x128 f16 = 4 KB
  float* wsumg   = (float*)(wneg + 16 * HDIM);             // 4 f32

  gemm_lds<<<dim3(256), 256, 0, stream>>>(rec, lig, W1, b1, cw, hid, wneg, wsumg);
  bilinear_max<<<dim3(NT, NT, BDIM), 512, 0, stream>>>(hid, wneg, wsumg, cw, cb, partial);
  finalize<<<dim3(BDIM), 64, 0, stream>>>(partial, out);
}